// Round 10
// baseline (305.583 us; speedup 1.0000x reference)
//
#include <hip/hip_runtime.h>
#include <math.h>

#define NN 50000
#define EE 800000
#define RR 2
#define LL 2
#define DD 128
#define GG 64
#define CCLS 8
#define NBUK 196     // buckets of 256 dst nodes: bucket = dst >> 8
#define BCAP 6144    // max edges per bucket (mean 4082, sigma 64)

typedef unsigned int uint;
typedef unsigned short ushort;
typedef short bf16x8 __attribute__((ext_vector_type(8)));
typedef float f32x4 __attribute__((ext_vector_type(4)));
typedef float f32x2 __attribute__((ext_vector_type(2)));

// ---------------- workspace layout (bytes) ----------------
#define OFF_XW    ((size_t)0)           // [2][N][128] fp8 e4m3 (isd-scaled) 12,800,000
#define OFF_H1    ((size_t)12800000)    // [N][64] uint (packed bf16)      12,800,000
#define OFF_WBT   ((size_t)25600000)    // [L][R][128][128] bf16              131,072
#define OFF_ISD   ((size_t)25731072)    // [2][N] f32                         400,000
#define OFF_RP    ((size_t)26131072)    // [2][N+1] i32                       400,064
#define OFF_CI    ((size_t)26531136)    // [2][E] i32 (+64B guard)          6,400,064
#define OFF_BD    ((size_t)32931200)    // [2][196][6144] uint              9,633,792
#define OFF_GCUR  ((size_t)42564992)    // [2][196] i32 bucket counters (1600 B)

static __device__ __forceinline__ ushort f2b(float f) {
  uint u = __float_as_uint(f);
  uint r = (u + 0x7fffu + ((u >> 16) & 1u)) >> 16;
  return (ushort)r;
}
static __device__ __forceinline__ float blo(uint u) { return __uint_as_float(u << 16); }
static __device__ __forceinline__ float bhi(uint u) { return __uint_as_float(u & 0xffff0000u); }

// ---------------- W prep: fp32 W[l][r][k][n] -> bf16 WbfT[l][r][n][k] ----------------
__global__ __launch_bounds__(256) void k_wprep(const float* __restrict__ W,
                                               ushort* __restrict__ WT) {
  int idx = blockIdx.x * 256 + threadIdx.x;  // 65536 total
  int lr = idx >> 14;
  int rem = idx & 16383;
  int n = rem >> 7, k = rem & 127;
  WT[lr * 16384 + n * 128 + k] = f2b(W[lr * 16384 + k * 128 + n]);
}

// ---------------- phase 1: partition edges into dst buckets (coalesced) ----------------
__global__ __launch_bounds__(256) void k_part(const int* __restrict__ EI,
                                              int* __restrict__ gcur,
                                              uint* __restrict__ bdata) {
  __shared__ int hist[256];   // bucket counts -> stage-exclusive offsets
  __shared__ int sbase[256];  // scan scratch
  __shared__ int gbase[256];  // global reservation base per bucket
  __shared__ int lcur[256];
  __shared__ uint stage[4096];
  __shared__ unsigned char bstage[4096];
  const int r = blockIdx.y;
  const int t = threadIdx.x;
  const int e0 = blockIdx.x * 4096;
  const int cnt = min(4096, EE - e0);
  hist[t] = 0;
  lcur[t] = 0;
  __syncthreads();

  int src[16], dst[16];
  bool val[4];
#pragma unroll
  for (int j = 0; j < 4; ++j) {
    int i4 = (j * 256 + t) * 4;
    val[j] = (i4 < cnt);
    if (val[j]) {
      int4 s4 = *(const int4*)(EI + (size_t)r * 2 * EE + e0 + i4);
      int4 d4 = *(const int4*)(EI + (size_t)r * 2 * EE + EE + e0 + i4);
      src[j * 4 + 0] = s4.x; src[j * 4 + 1] = s4.y; src[j * 4 + 2] = s4.z; src[j * 4 + 3] = s4.w;
      dst[j * 4 + 0] = d4.x; dst[j * 4 + 1] = d4.y; dst[j * 4 + 2] = d4.z; dst[j * 4 + 3] = d4.w;
#pragma unroll
      for (int i = 0; i < 4; ++i) atomicAdd(&hist[dst[j * 4 + i] >> 8], 1);
    }
  }
  __syncthreads();
  int hv = hist[t];
  if (t < NBUK && hv > 0)
    gbase[t] = atomicAdd(&gcur[r * NBUK + t], hv);
  else
    gbase[t] = 0;
  sbase[t] = hv;
  __syncthreads();
  for (int off = 1; off < 256; off <<= 1) {
    int u = (t >= off) ? sbase[t - off] : 0;
    __syncthreads();
    sbase[t] += u;
    __syncthreads();
  }
  int incl = sbase[t];
  hist[t] = incl - hv;  // exclusive stage offset
  __syncthreads();
#pragma unroll
  for (int j = 0; j < 4; ++j) {
    if (val[j]) {
#pragma unroll
      for (int i = 0; i < 4; ++i) {
        int d = dst[j * 4 + i];
        int b = d >> 8;
        int p = atomicAdd(&lcur[b], 1);
        int pos = hist[b] + p;
        stage[pos] = ((uint)src[j * 4 + i] << 8) | (uint)(d & 255);
        bstage[pos] = (unsigned char)b;
      }
    }
  }
  __syncthreads();
  for (int s = t; s < cnt; s += 256) {
    int b = (int)bstage[s];
    bdata[(size_t)(r * NBUK + b) * BCAP + gbase[b] + (s - hist[b])] = stage[s];
  }
}

// ---------------- phase 2: per-bucket CSR (deg, isd, rp, ci) all coalesced ----------------
__global__ __launch_bounds__(256) void k_csr(const uint* __restrict__ bdata,
                                             const int* __restrict__ gcur,
                                             float* __restrict__ isd,
                                             int* __restrict__ rp,
                                             int* __restrict__ ci) {
  __shared__ int lcnt[256];
  __shared__ int lrp[256];
  __shared__ int lcur[256];
  __shared__ int cstage[BCAP];
  __shared__ int basesh;
  const int b = blockIdx.x;
  const int r = blockIdx.y;
  const int t = threadIdx.x;
  const int cnt = gcur[r * NBUK + b];
  // bucket base = prefix sum of gcur[r][0..b-1] (NBUK <= 256: 1 elem/thread)
  lcnt[t] = (t < b) ? gcur[r * NBUK + t] : 0;
  __syncthreads();
  for (int off = 128; off > 0; off >>= 1) {
    if (t < off) lcnt[t] += lcnt[t + off];
    __syncthreads();
  }
  if (t == 0) basesh = lcnt[0];
  __syncthreads();
  const int base = basesh;
  const uint* bd = bdata + (size_t)(r * NBUK + b) * BCAP;
  __syncthreads();
  lcnt[t] = 0;
  lcur[t] = 0;
  __syncthreads();
  for (int s = t; s < cnt; s += 256) {
    uint pr = bd[s];
    atomicAdd(&lcnt[pr & 255u], 1);
  }
  __syncthreads();
  int deg = lcnt[t];
  lrp[t] = deg;
  __syncthreads();
  for (int off = 1; off < 256; off <<= 1) {
    int u = (t >= off) ? lrp[t - off] : 0;
    __syncthreads();
    lrp[t] += u;
    __syncthreads();
  }
  int incl = lrp[t];
  __syncthreads();
  lrp[t] = incl - deg;  // exclusive
  __syncthreads();
  int node = b * 256 + t;
  if (node < NN) {
    isd[r * NN + node] = rsqrtf((float)(deg + 1));
    rp[r * (NN + 1) + node] = base + lrp[t];
  }
  if (b == NBUK - 1 && t == 0) rp[r * (NN + 1) + NN] = EE;
  for (int s = t; s < cnt; s += 256) {
    uint pr = bd[s];
    int j = (int)(pr & 255u);
    int p = atomicAdd(&lcur[j], 1);
    cstage[lrp[j] + p] = (int)(pr >> 8);
  }
  __syncthreads();
  for (int s = t; s < cnt; s += 256) ci[(size_t)r * EE + base + s] = cstage[s];
}

// ---------------- MFMA GEMM (relation-merged): per block, stage A once (full K),
// then for r in {0,1}: stage W_r, compute, write xw'[r] = (X @ W[r]) * isd[r] as fp8 ----
#define TS 136   // 128+8 ushorts: shared row stride for A and WT tiles
template <int IN_BF16>
__global__ __launch_bounds__(256) void k_gemm(const void* __restrict__ Xv,
                                              const ushort* __restrict__ WTg,
                                              const float* __restrict__ isd,
                                              uint* __restrict__ Y) {
  __shared__ ushort WTl[128 * TS];  // 34.8 KB
  __shared__ ushort Al[128 * TS];   // 34.8 KB
  const int m0b = blockIdx.x * 128;
  const int t = threadIdx.x;
  const int w = t >> 6, L = t & 63, q = L >> 4, ln = L & 15;

  // stage A full-K: rows 128 x 128 cols (two 64-col halves)
#pragma unroll
  for (int hh = 0; hh < 2; ++hh) {
    int row = t >> 1, ch = t & 1;
    int gm = m0b + row;
    ushort* dst = &Al[row * TS + hh * 64 + ch * 32];
    if (gm < NN) {
      if (IN_BF16) {
        const uint4* xp = (const uint4*)((const ushort*)Xv + (size_t)gm * 128 + hh * 64 + ch * 32);
#pragma unroll
        for (int j = 0; j < 4; ++j) ((uint4*)dst)[j] = xp[j];
      } else {
        const float4* xp = (const float4*)((const float*)Xv + (size_t)gm * 128 + hh * 64 + ch * 32);
        ushort tmp[32];
#pragma unroll
        for (int j = 0; j < 8; ++j) {
          float4 v = xp[j];
          tmp[j * 4 + 0] = f2b(v.x); tmp[j * 4 + 1] = f2b(v.y);
          tmp[j * 4 + 2] = f2b(v.z); tmp[j * 4 + 3] = f2b(v.w);
        }
#pragma unroll
        for (int j = 0; j < 4; ++j) ((uint4*)dst)[j] = ((uint4*)tmp)[j];
      }
    } else {
      uint4 z = make_uint4(0, 0, 0, 0);
#pragma unroll
      for (int j = 0; j < 4; ++j) ((uint4*)dst)[j] = z;
    }
  }

  for (int r = 0; r < RR; ++r) {
    __syncthreads();  // A ready / previous r's WT reads done
    {
      const ushort* WTr = WTg + (size_t)r * 16384;
#pragma unroll
      for (int i = 0; i < 8; ++i) {
        int g = t + i * 256;
        int n = g >> 4, k0 = (g & 15) * 8;
        *(uint4*)(&WTl[n * TS + k0]) = *(const uint4*)(WTr + n * 128 + k0);
      }
    }
    __syncthreads();

    f32x4 acc[2][8];
#pragma unroll
    for (int mt = 0; mt < 2; ++mt)
#pragma unroll
      for (int nt = 0; nt < 8; ++nt) {
        acc[mt][nt][0] = 0.f; acc[mt][nt][1] = 0.f;
        acc[mt][nt][2] = 0.f; acc[mt][nt][3] = 0.f;
      }
#pragma unroll
    for (int kk = 0; kk < 4; ++kk) {
      bf16x8 b0 = *(const bf16x8*)(&Al[(w * 32 + ln) * TS + kk * 32 + q * 8]);
      bf16x8 b1 = *(const bf16x8*)(&Al[(w * 32 + 16 + ln) * TS + kk * 32 + q * 8]);
#pragma unroll
      for (int nt = 0; nt < 8; ++nt) {
        bf16x8 a = *(const bf16x8*)(&WTl[(nt * 16 + ln) * TS + kk * 32 + q * 8]);
        acc[0][nt] = __builtin_amdgcn_mfma_f32_16x16x32_bf16(a, b0, acc[0][nt], 0, 0, 0);
        acc[1][nt] = __builtin_amdgcn_mfma_f32_16x16x32_bf16(a, b1, acc[1][nt], 0, 0, 0);
      }
    }
    // epilogue: lane holds D for m = m0b + w*32 + mt*16 + ln, n = nt*16 + q*4 + reg
    uint* Yr = Y + (size_t)r * NN * 32;
#pragma unroll
    for (int mt = 0; mt < 2; ++mt) {
      int m = m0b + w * 32 + mt * 16 + ln;
      if (m < NN) {
        float sc = isd[r * NN + m];
        uint* yp = Yr + (size_t)m * 32;
#pragma unroll
        for (int nt = 0; nt < 8; ++nt) {
          f32x4 v = acc[mt][nt];
          uint u = __builtin_amdgcn_cvt_pk_fp8_f32(v[0] * sc, v[1] * sc, 0u, false);
          u = __builtin_amdgcn_cvt_pk_fp8_f32(v[2] * sc, v[3] * sc, u, true);
          yp[nt * 4 + q] = u;
        }
      }
    }
  }
}

// ---------------- aggregation (R7-proven): 1 wave/node, 8 edges/batch, fp8 gathers -------
__global__ __launch_bounds__(256) void k_agg(const uint* __restrict__ xw,
                                             const int* __restrict__ rp,
                                             const int* __restrict__ ci,
                                             const float* __restrict__ isd,
                                             const float* __restrict__ bias,
                                             uint* __restrict__ hout, int relu_flag) {
  const int w = threadIdx.x >> 6;
  const int lane = threadIdx.x & 63;
  const int g = lane >> 3, c = lane & 7;
  const int i = blockIdx.x * 4 + w;

  f32x2 tot[8];
#pragma unroll
  for (int k = 0; k < 8; ++k) { tot[k][0] = 0.f; tot[k][1] = 0.f; }

#pragma unroll
  for (int r = 0; r < RR; ++r) {
    const char* xbase = (const char*)(xw + (size_t)r * NN * 32);  // fp8 rows, 128 B each
    const int* cir = ci + (size_t)r * EE;
    const float di = isd[r * NN + i];
    const int e0 = rp[r * (NN + 1) + i];
    const int cnt = rp[r * (NN + 1) + i + 1] - e0;
    const int total = cnt + 1;  // + self (virtual edge idx == cnt, s = i)
    const uint coff = (uint)c * 16u;

    f32x2 acc[8];
#pragma unroll
    for (int k = 0; k < 8; ++k) { acc[k][0] = 0.f; acc[k][1] = 0.f; }

    int s_cur = (g < cnt) ? cir[e0 + g] : i;
    for (int base = 0; base < total; base += 8) {
      int idxn = base + 8 + g;
      int s_next = (idxn < cnt) ? cir[e0 + idxn] : i;  // prefetch next slot's index
      if (base + g < total) {
        uint4 u = *(const uint4*)(xbase + ((uint)s_cur * 128u + coff));
        acc[0] += __builtin_amdgcn_cvt_pk_f32_fp8(u.x, false);
        acc[1] += __builtin_amdgcn_cvt_pk_f32_fp8(u.x, true);
        acc[2] += __builtin_amdgcn_cvt_pk_f32_fp8(u.y, false);
        acc[3] += __builtin_amdgcn_cvt_pk_f32_fp8(u.y, true);
        acc[4] += __builtin_amdgcn_cvt_pk_f32_fp8(u.z, false);
        acc[5] += __builtin_amdgcn_cvt_pk_f32_fp8(u.z, true);
        acc[6] += __builtin_amdgcn_cvt_pk_f32_fp8(u.w, false);
        acc[7] += __builtin_amdgcn_cvt_pk_f32_fp8(u.w, true);
      }
      s_cur = s_next;
    }
    f32x2 di2; di2[0] = di; di2[1] = di;
#pragma unroll
    for (int k = 0; k < 8; ++k) tot[k] += acc[k] * di2;  // v_pk_fma_f32
  }

  // reduce over the 8 edge slots (lane bits 3,4,5)
  float* tf = (float*)tot;
#pragma unroll
  for (int mask = 8; mask <= 32; mask <<= 1) {
#pragma unroll
    for (int k = 0; k < 16; ++k) tf[k] += __shfl_xor(tf[k], mask);
  }

  // lanes g<2 write: lane (g,c) stores channels [c*16 + g*8, +8) as 4 packed uints
  if (g < 2) {
    int ch0 = c * 16 + g * 8;
    const float4* bp = (const float4*)(bias + ch0);
    const float4* bq = (const float4*)(bias + DD + ch0);
    float4 b0 = bp[0], b1 = bp[1], b2 = bq[0], b3 = bq[1];
    float o[8];
#pragma unroll
    for (int j = 0; j < 8; ++j) o[j] = (g == 0) ? tf[j] : tf[8 + j];
    o[0] += b0.x + b2.x; o[1] += b0.y + b2.y; o[2] += b0.z + b2.z; o[3] += b0.w + b2.w;
    o[4] += b1.x + b3.x; o[5] += b1.y + b3.y; o[6] += b1.z + b3.z; o[7] += b1.w + b3.w;
    if (relu_flag) {
#pragma unroll
      for (int j = 0; j < 8; ++j) o[j] = fmaxf(o[j], 0.f);
    }
    uint4 pk;
    pk.x = (uint)f2b(o[0]) | ((uint)f2b(o[1]) << 16);
    pk.y = (uint)f2b(o[2]) | ((uint)f2b(o[3]) << 16);
    pk.z = (uint)f2b(o[4]) | ((uint)f2b(o[5]) << 16);
    pk.w = (uint)f2b(o[6]) | ((uint)f2b(o[7]) << 16);
    ((uint4*)(hout + (size_t)i * 64))[c * 2 + g] = pk;
  }
}

// ---------------- fused mean-pool + linear head: 1 block per graph ----------------
// batch sorted ascending: graph g owns [lower_bound(g), lower_bound(g+1)).
__global__ __launch_bounds__(64) void k_poolfinal(const uint* __restrict__ h,
                                                  const int* __restrict__ batch,
                                                  const float* __restrict__ lin_w,
                                                  const float* __restrict__ lin_b,
                                                  float* __restrict__ out) {
  const int g = blockIdx.x;
  const int lane = threadIdx.x;
  // lower_bound(batch, g) and lower_bound(batch, g+1)
  int lo = 0, hi2 = NN;
  while (lo < hi2) { int mid = (lo + hi2) >> 1; if (batch[mid] < g) lo = mid + 1; else hi2 = mid; }
  int hi = lo, hh = NN;
  while (hi < hh) { int mid = (hi + hh) >> 1; if (batch[mid] < g + 1) hi = mid + 1; else hh = mid; }

  float aLo = 0.f, aHi = 0.f;
  int n = lo;
  for (; n + 4 <= hi; n += 4) {
    uint u0 = h[(size_t)(n + 0) * 64 + lane];
    uint u1 = h[(size_t)(n + 1) * 64 + lane];
    uint u2 = h[(size_t)(n + 2) * 64 + lane];
    uint u3 = h[(size_t)(n + 3) * 64 + lane];
    aLo += blo(u0) + blo(u1) + blo(u2) + blo(u3);
    aHi += bhi(u0) + bhi(u1) + bhi(u2) + bhi(u3);
  }
  for (; n < hi; ++n) {
    uint u = h[(size_t)n * 64 + lane];
    aLo += blo(u);
    aHi += bhi(u);
  }
  int cnt = hi - lo;
  float inv = 1.f / (float)max(cnt, 1);
  float mLo = aLo * inv, mHi = aHi * inv;

  // head: lane holds channels d0 = 2*lane, d1 = 2*lane+1; lin_w is [D][C]
  const int d0 = lane * 2;
  float p[CCLS];
  const float4* w0 = (const float4*)(lin_w + d0 * CCLS);       // 8 floats = 2x float4
  const float4* w1 = (const float4*)(lin_w + (d0 + 1) * CCLS);
  float4 a0 = w0[0], a1 = w0[1], c0 = w1[0], c1 = w1[1];
  p[0] = mLo * a0.x + mHi * c0.x; p[1] = mLo * a0.y + mHi * c0.y;
  p[2] = mLo * a0.z + mHi * c0.z; p[3] = mLo * a0.w + mHi * c0.w;
  p[4] = mLo * a1.x + mHi * c1.x; p[5] = mLo * a1.y + mHi * c1.y;
  p[6] = mLo * a1.z + mHi * c1.z; p[7] = mLo * a1.w + mHi * c1.w;
#pragma unroll
  for (int mask = 1; mask <= 32; mask <<= 1) {
#pragma unroll
    for (int cc = 0; cc < CCLS; ++cc) p[cc] += __shfl_xor(p[cc], mask);
  }
  if (lane == 0) {
#pragma unroll
    for (int cc = 0; cc < CCLS; ++cc) out[g * CCLS + cc] = p[cc] + lin_b[cc];
  }
}

extern "C" void kernel_launch(void* const* d_in, const int* in_sizes, int n_in,
                              void* d_out, int out_size, void* d_ws, size_t ws_size,
                              hipStream_t stream) {
  (void)in_sizes; (void)n_in; (void)out_size; (void)ws_size;
  const float* x     = (const float*)d_in[0];
  const float* W     = (const float*)d_in[1];
  const float* b     = (const float*)d_in[2];
  const float* lin_w = (const float*)d_in[3];
  const float* lin_b = (const float*)d_in[4];
  const int*   EI    = (const int*)d_in[5];
  const int*   batch = (const int*)d_in[6];
  float* out = (float*)d_out;

  char* ws = (char*)d_ws;
  uint*   xw    = (uint*)(ws + OFF_XW);       // fp8 table (isd-prescaled)
  uint*   h1    = (uint*)(ws + OFF_H1);       // bf16 packed
  ushort* WbfT  = (ushort*)(ws + OFF_WBT);
  float*  isd   = (float*)(ws + OFF_ISD);
  int*    rp    = (int*)(ws + OFF_RP);
  int*    ci    = (int*)(ws + OFF_CI);
  uint*   bdata = (uint*)(ws + OFF_BD);
  int*    gcur  = (int*)(ws + OFF_GCUR);

  (void)hipMemsetAsync(gcur, 0, 1600, stream);

  k_wprep<<<256, 256, 0, stream>>>(W, WbfT);
  k_part<<<dim3((EE + 4095) / 4096, RR), 256, 0, stream>>>(EI, gcur, bdata);
  k_csr<<<dim3(NBUK, RR), 256, 0, stream>>>(bdata, gcur, isd, rp, ci);

  for (int l = 0; l < LL; ++l) {
    const ushort* WTl_g = WbfT + (size_t)l * RR * DD * DD;
    if (l == 0)
      k_gemm<0><<<(NN + 127) / 128, 256, 0, stream>>>((const void*)x, WTl_g, isd, xw);
    else
      k_gemm<1><<<(NN + 127) / 128, 256, 0, stream>>>((const void*)h1, WTl_g, isd, xw);
    k_agg<<<(NN + 3) / 4, 256, 0, stream>>>(xw, rp, ci, isd,
                                            b + (size_t)l * RR * DD, h1,
                                            (l < LL - 1) ? 1 : 0);
  }
  k_poolfinal<<<GG, 64, 0, stream>>>(h1, batch, lin_w, lin_b, out);
}

// Round 11
// 257.857 us; speedup vs baseline: 1.1851x; 1.1851x over previous
//
#include <hip/hip_runtime.h>
#include <math.h>

#define NN 50000
#define EE 800000
#define RR 2
#define LL 2
#define DD 128
#define GG 64
#define CCLS 8
#define NBUK 196     // buckets of 256 dst nodes: bucket = dst >> 8
#define BCAP 6144    // max edges per bucket (mean 4082, sigma 64)

typedef unsigned int uint;
typedef unsigned short ushort;
typedef short bf16x8 __attribute__((ext_vector_type(8)));
typedef float f32x4 __attribute__((ext_vector_type(4)));
typedef float f32x2 __attribute__((ext_vector_type(2)));

// ---------------- workspace layout (bytes) ----------------
#define OFF_XW    ((size_t)0)           // [2][N][128] fp8 e4m3 (isd-scaled) 12,800,000
#define OFF_H1    ((size_t)12800000)    // [N][64] uint (packed bf16)      12,800,000
#define OFF_WBT   ((size_t)25600000)    // [L][R][128][128] bf16              131,072
#define OFF_ISD   ((size_t)25731072)    // [2][N] f32                         400,000
#define OFF_RP    ((size_t)26131072)    // [2][N+1] i32                       400,064
#define OFF_CI    ((size_t)26531136)    // [2][E] i32 (+64B guard)          6,400,064
#define OFF_BD    ((size_t)32931200)    // [2][196][6144] uint              9,633,792
#define OFF_ZERO  ((size_t)42564992)
// zero region internal offsets (bytes)
#define ZO_GCUR 0        // [2][196] i32 bucket counters (1568 B, pad 1600)
#define ZO_SUM  1600     // [G][D] f32 (32768 B)
#define ZO_CNT  34368    // [G] i32 (256 B)
#define ZERO_BYTES 34624

static __device__ __forceinline__ ushort f2b(float f) {
  uint u = __float_as_uint(f);
  uint r = (u + 0x7fffu + ((u >> 16) & 1u)) >> 16;
  return (ushort)r;
}
static __device__ __forceinline__ float blo(uint u) { return __uint_as_float(u << 16); }
static __device__ __forceinline__ float bhi(uint u) { return __uint_as_float(u & 0xffff0000u); }

// ---------------- W prep: fp32 W[l][r][k][n] -> bf16 WbfT[l][r][n][k] ----------------
__global__ __launch_bounds__(256) void k_wprep(const float* __restrict__ W,
                                               ushort* __restrict__ WT) {
  int idx = blockIdx.x * 256 + threadIdx.x;  // 65536 total
  int lr = idx >> 14;
  int rem = idx & 16383;
  int n = rem >> 7, k = rem & 127;
  WT[lr * 16384 + n * 128 + k] = f2b(W[lr * 16384 + k * 128 + n]);
}

// ---------------- phase 1: partition edges into dst buckets (coalesced) ----------------
__global__ __launch_bounds__(256) void k_part(const int* __restrict__ EI,
                                              int* __restrict__ gcur,
                                              uint* __restrict__ bdata) {
  __shared__ int hist[256];   // bucket counts -> stage-exclusive offsets
  __shared__ int sbase[256];  // scan scratch
  __shared__ int gbase[256];  // global reservation base per bucket
  __shared__ int lcur[256];
  __shared__ uint stage[4096];
  __shared__ unsigned char bstage[4096];
  const int r = blockIdx.y;
  const int t = threadIdx.x;
  const int e0 = blockIdx.x * 4096;
  const int cnt = min(4096, EE - e0);
  hist[t] = 0;
  lcur[t] = 0;
  __syncthreads();

  int src[16], dst[16];
  bool val[4];
#pragma unroll
  for (int j = 0; j < 4; ++j) {
    int i4 = (j * 256 + t) * 4;
    val[j] = (i4 < cnt);
    if (val[j]) {
      int4 s4 = *(const int4*)(EI + (size_t)r * 2 * EE + e0 + i4);
      int4 d4 = *(const int4*)(EI + (size_t)r * 2 * EE + EE + e0 + i4);
      src[j * 4 + 0] = s4.x; src[j * 4 + 1] = s4.y; src[j * 4 + 2] = s4.z; src[j * 4 + 3] = s4.w;
      dst[j * 4 + 0] = d4.x; dst[j * 4 + 1] = d4.y; dst[j * 4 + 2] = d4.z; dst[j * 4 + 3] = d4.w;
#pragma unroll
      for (int i = 0; i < 4; ++i) atomicAdd(&hist[dst[j * 4 + i] >> 8], 1);
    }
  }
  __syncthreads();
  int hv = hist[t];
  if (t < NBUK && hv > 0)
    gbase[t] = atomicAdd(&gcur[r * NBUK + t], hv);
  else
    gbase[t] = 0;
  sbase[t] = hv;
  __syncthreads();
  for (int off = 1; off < 256; off <<= 1) {
    int u = (t >= off) ? sbase[t - off] : 0;
    __syncthreads();
    sbase[t] += u;
    __syncthreads();
  }
  int incl = sbase[t];
  hist[t] = incl - hv;  // exclusive stage offset
  __syncthreads();
#pragma unroll
  for (int j = 0; j < 4; ++j) {
    if (val[j]) {
#pragma unroll
      for (int i = 0; i < 4; ++i) {
        int d = dst[j * 4 + i];
        int b = d >> 8;
        int p = atomicAdd(&lcur[b], 1);
        int pos = hist[b] + p;
        stage[pos] = ((uint)src[j * 4 + i] << 8) | (uint)(d & 255);
        bstage[pos] = (unsigned char)b;
      }
    }
  }
  __syncthreads();
  for (int s = t; s < cnt; s += 256) {
    int b = (int)bstage[s];
    bdata[(size_t)(r * NBUK + b) * BCAP + gbase[b] + (s - hist[b])] = stage[s];
  }
}

// ---------------- phase 2: per-bucket CSR (deg, isd, rp, ci) all coalesced ----------------
__global__ __launch_bounds__(256) void k_csr(const uint* __restrict__ bdata,
                                             const int* __restrict__ gcur,
                                             float* __restrict__ isd,
                                             int* __restrict__ rp,
                                             int* __restrict__ ci) {
  __shared__ int lcnt[256];
  __shared__ int lrp[256];
  __shared__ int lcur[256];
  __shared__ int cstage[BCAP];
  __shared__ int basesh;
  const int b = blockIdx.x;
  const int r = blockIdx.y;
  const int t = threadIdx.x;
  const int cnt = gcur[r * NBUK + b];
  // bucket base = prefix sum of gcur[r][0..b-1] (NBUK <= 256: 1 elem/thread)
  lcnt[t] = (t < b) ? gcur[r * NBUK + t] : 0;
  __syncthreads();
  for (int off = 128; off > 0; off >>= 1) {
    if (t < off) lcnt[t] += lcnt[t + off];
    __syncthreads();
  }
  if (t == 0) basesh = lcnt[0];
  __syncthreads();
  const int base = basesh;
  const uint* bd = bdata + (size_t)(r * NBUK + b) * BCAP;
  __syncthreads();
  lcnt[t] = 0;
  lcur[t] = 0;
  __syncthreads();
  for (int s = t; s < cnt; s += 256) {
    uint pr = bd[s];
    atomicAdd(&lcnt[pr & 255u], 1);
  }
  __syncthreads();
  int deg = lcnt[t];
  lrp[t] = deg;
  __syncthreads();
  for (int off = 1; off < 256; off <<= 1) {
    int u = (t >= off) ? lrp[t - off] : 0;
    __syncthreads();
    lrp[t] += u;
    __syncthreads();
  }
  int incl = lrp[t];
  __syncthreads();
  lrp[t] = incl - deg;  // exclusive
  __syncthreads();
  int node = b * 256 + t;
  if (node < NN) {
    isd[r * NN + node] = rsqrtf((float)(deg + 1));
    rp[r * (NN + 1) + node] = base + lrp[t];
  }
  if (b == NBUK - 1 && t == 0) rp[r * (NN + 1) + NN] = EE;
  for (int s = t; s < cnt; s += 256) {
    uint pr = bd[s];
    int j = (int)(pr & 255u);
    int p = atomicAdd(&lcur[j], 1);
    cstage[lrp[j] + p] = (int)(pr >> 8);
  }
  __syncthreads();
  for (int s = t; s < cnt; s += 256) ci[(size_t)r * EE + base + s] = cstage[s];
}

// ---------------- MFMA GEMM (relation-merged): per block, stage A once (full K),
// then for r in {0,1}: stage W_r, compute, write xw'[r] = (X @ W[r]) * isd[r] as fp8 ----
#define TS 136   // 128+8 ushorts: shared row stride for A and WT tiles
template <int IN_BF16>
__global__ __launch_bounds__(256) void k_gemm(const void* __restrict__ Xv,
                                              const ushort* __restrict__ WTg,
                                              const float* __restrict__ isd,
                                              uint* __restrict__ Y) {
  __shared__ ushort WTl[128 * TS];  // 34.8 KB
  __shared__ ushort Al[128 * TS];   // 34.8 KB
  const int m0b = blockIdx.x * 128;
  const int t = threadIdx.x;
  const int w = t >> 6, L = t & 63, q = L >> 4, ln = L & 15;

  // stage A full-K: rows 128 x 128 cols (two 64-col halves)
#pragma unroll
  for (int hh = 0; hh < 2; ++hh) {
    int row = t >> 1, ch = t & 1;
    int gm = m0b + row;
    ushort* dst = &Al[row * TS + hh * 64 + ch * 32];
    if (gm < NN) {
      if (IN_BF16) {
        const uint4* xp = (const uint4*)((const ushort*)Xv + (size_t)gm * 128 + hh * 64 + ch * 32);
#pragma unroll
        for (int j = 0; j < 4; ++j) ((uint4*)dst)[j] = xp[j];
      } else {
        const float4* xp = (const float4*)((const float*)Xv + (size_t)gm * 128 + hh * 64 + ch * 32);
        ushort tmp[32];
#pragma unroll
        for (int j = 0; j < 8; ++j) {
          float4 v = xp[j];
          tmp[j * 4 + 0] = f2b(v.x); tmp[j * 4 + 1] = f2b(v.y);
          tmp[j * 4 + 2] = f2b(v.z); tmp[j * 4 + 3] = f2b(v.w);
        }
#pragma unroll
        for (int j = 0; j < 4; ++j) ((uint4*)dst)[j] = ((uint4*)tmp)[j];
      }
    } else {
      uint4 z = make_uint4(0, 0, 0, 0);
#pragma unroll
      for (int j = 0; j < 4; ++j) ((uint4*)dst)[j] = z;
    }
  }

  for (int r = 0; r < RR; ++r) {
    __syncthreads();  // A ready / previous r's WT reads done
    {
      const ushort* WTr = WTg + (size_t)r * 16384;
#pragma unroll
      for (int i = 0; i < 8; ++i) {
        int g = t + i * 256;
        int n = g >> 4, k0 = (g & 15) * 8;
        *(uint4*)(&WTl[n * TS + k0]) = *(const uint4*)(WTr + n * 128 + k0);
      }
    }
    __syncthreads();

    f32x4 acc[2][8];
#pragma unroll
    for (int mt = 0; mt < 2; ++mt)
#pragma unroll
      for (int nt = 0; nt < 8; ++nt) {
        acc[mt][nt][0] = 0.f; acc[mt][nt][1] = 0.f;
        acc[mt][nt][2] = 0.f; acc[mt][nt][3] = 0.f;
      }
#pragma unroll
    for (int kk = 0; kk < 4; ++kk) {
      bf16x8 b0 = *(const bf16x8*)(&Al[(w * 32 + ln) * TS + kk * 32 + q * 8]);
      bf16x8 b1 = *(const bf16x8*)(&Al[(w * 32 + 16 + ln) * TS + kk * 32 + q * 8]);
#pragma unroll
      for (int nt = 0; nt < 8; ++nt) {
        bf16x8 a = *(const bf16x8*)(&WTl[(nt * 16 + ln) * TS + kk * 32 + q * 8]);
        acc[0][nt] = __builtin_amdgcn_mfma_f32_16x16x32_bf16(a, b0, acc[0][nt], 0, 0, 0);
        acc[1][nt] = __builtin_amdgcn_mfma_f32_16x16x32_bf16(a, b1, acc[1][nt], 0, 0, 0);
      }
    }
    // epilogue: lane holds D for m = m0b + w*32 + mt*16 + ln, n = nt*16 + q*4 + reg
    uint* Yr = Y + (size_t)r * NN * 32;
#pragma unroll
    for (int mt = 0; mt < 2; ++mt) {
      int m = m0b + w * 32 + mt * 16 + ln;
      if (m < NN) {
        float sc = isd[r * NN + m];
        uint* yp = Yr + (size_t)m * 32;
#pragma unroll
        for (int nt = 0; nt < 8; ++nt) {
          f32x4 v = acc[mt][nt];
          uint u = __builtin_amdgcn_cvt_pk_fp8_f32(v[0] * sc, v[1] * sc, 0u, false);
          u = __builtin_amdgcn_cvt_pk_fp8_f32(v[2] * sc, v[3] * sc, u, true);
          yp[nt * 4 + q] = u;
        }
      }
    }
  }
}

// ---------------- aggregation (R7-proven): 1 wave/node, 8 edges/batch, fp8 gathers -------
__global__ __launch_bounds__(256) void k_agg(const uint* __restrict__ xw,
                                             const int* __restrict__ rp,
                                             const int* __restrict__ ci,
                                             const float* __restrict__ isd,
                                             const float* __restrict__ bias,
                                             uint* __restrict__ hout, int relu_flag) {
  const int w = threadIdx.x >> 6;
  const int lane = threadIdx.x & 63;
  const int g = lane >> 3, c = lane & 7;
  const int i = blockIdx.x * 4 + w;

  f32x2 tot[8];
#pragma unroll
  for (int k = 0; k < 8; ++k) { tot[k][0] = 0.f; tot[k][1] = 0.f; }

#pragma unroll
  for (int r = 0; r < RR; ++r) {
    const char* xbase = (const char*)(xw + (size_t)r * NN * 32);  // fp8 rows, 128 B each
    const int* cir = ci + (size_t)r * EE;
    const float di = isd[r * NN + i];
    const int e0 = rp[r * (NN + 1) + i];
    const int cnt = rp[r * (NN + 1) + i + 1] - e0;
    const int total = cnt + 1;  // + self (virtual edge idx == cnt, s = i)
    const uint coff = (uint)c * 16u;

    f32x2 acc[8];
#pragma unroll
    for (int k = 0; k < 8; ++k) { acc[k][0] = 0.f; acc[k][1] = 0.f; }

    int s_cur = (g < cnt) ? cir[e0 + g] : i;
    for (int base = 0; base < total; base += 8) {
      int idxn = base + 8 + g;
      int s_next = (idxn < cnt) ? cir[e0 + idxn] : i;  // prefetch next slot's index
      if (base + g < total) {
        uint4 u = *(const uint4*)(xbase + ((uint)s_cur * 128u + coff));
        acc[0] += __builtin_amdgcn_cvt_pk_f32_fp8(u.x, false);
        acc[1] += __builtin_amdgcn_cvt_pk_f32_fp8(u.x, true);
        acc[2] += __builtin_amdgcn_cvt_pk_f32_fp8(u.y, false);
        acc[3] += __builtin_amdgcn_cvt_pk_f32_fp8(u.y, true);
        acc[4] += __builtin_amdgcn_cvt_pk_f32_fp8(u.z, false);
        acc[5] += __builtin_amdgcn_cvt_pk_f32_fp8(u.z, true);
        acc[6] += __builtin_amdgcn_cvt_pk_f32_fp8(u.w, false);
        acc[7] += __builtin_amdgcn_cvt_pk_f32_fp8(u.w, true);
      }
      s_cur = s_next;
    }
    f32x2 di2; di2[0] = di; di2[1] = di;
#pragma unroll
    for (int k = 0; k < 8; ++k) tot[k] += acc[k] * di2;  // v_pk_fma_f32
  }

  // reduce over the 8 edge slots (lane bits 3,4,5)
  float* tf = (float*)tot;
#pragma unroll
  for (int mask = 8; mask <= 32; mask <<= 1) {
#pragma unroll
    for (int k = 0; k < 16; ++k) tf[k] += __shfl_xor(tf[k], mask);
  }

  // lanes g<2 write: lane (g,c) stores channels [c*16 + g*8, +8) as 4 packed uints
  if (g < 2) {
    int ch0 = c * 16 + g * 8;
    const float4* bp = (const float4*)(bias + ch0);
    const float4* bq = (const float4*)(bias + DD + ch0);
    float4 b0 = bp[0], b1 = bp[1], b2 = bq[0], b3 = bq[1];
    float o[8];
#pragma unroll
    for (int j = 0; j < 8; ++j) o[j] = (g == 0) ? tf[j] : tf[8 + j];
    o[0] += b0.x + b2.x; o[1] += b0.y + b2.y; o[2] += b0.z + b2.z; o[3] += b0.w + b2.w;
    o[4] += b1.x + b3.x; o[5] += b1.y + b3.y; o[6] += b1.z + b3.z; o[7] += b1.w + b3.w;
    if (relu_flag) {
#pragma unroll
      for (int j = 0; j < 8; ++j) o[j] = fmaxf(o[j], 0.f);
    }
    uint4 pk;
    pk.x = (uint)f2b(o[0]) | ((uint)f2b(o[1]) << 16);
    pk.y = (uint)f2b(o[2]) | ((uint)f2b(o[3]) << 16);
    pk.z = (uint)f2b(o[4]) | ((uint)f2b(o[5]) << 16);
    pk.w = (uint)f2b(o[6]) | ((uint)f2b(o[7]) << 16);
    ((uint4*)(hout + (size_t)i * 64))[c * 2 + g] = pk;
  }
}

// ---------------- pooling (R5-proven): 32 nodes/block, boundary-flush atomics ----------
#define PCHUNK 32
__global__ __launch_bounds__(64) void k_pool(const uint* __restrict__ h,
                                             const int* __restrict__ batch,
                                             float* __restrict__ sums,
                                             int* __restrict__ counts) {
  int lane = threadIdx.x;
  int n0 = blockIdx.x * PCHUNK;
  int n1 = n0 + PCHUNK;
  if (n1 > NN) n1 = NN;
  if (n0 >= NN) return;
  float aLo = 0.f, aHi = 0.f;
  int cnt = 0;
  int g = batch[n0];
  uint u = h[(size_t)n0 * 64 + lane];
  for (int n = n0; n < n1; ++n) {
    uint unext = 0;
    int gnext = g;
    if (n + 1 < n1) {
      unext = h[(size_t)(n + 1) * 64 + lane];
      gnext = batch[n + 1];
    }
    aLo += blo(u);
    aHi += bhi(u);
    cnt++;
    if (n + 1 < n1 && gnext != g) {
      atomicAdd(&sums[g * DD + lane * 2], aLo);
      atomicAdd(&sums[g * DD + lane * 2 + 1], aHi);
      if (lane == 0) atomicAdd(&counts[g], cnt);
      aLo = 0.f; aHi = 0.f; cnt = 0;
      g = gnext;
    }
    u = unext;
  }
  atomicAdd(&sums[g * DD + lane * 2], aLo);
  atomicAdd(&sums[g * DD + lane * 2 + 1], aHi);
  if (lane == 0) atomicAdd(&counts[g], cnt);
}

__global__ __launch_bounds__(512) void k_final(const float* __restrict__ sums,
                                               const int* __restrict__ counts,
                                               const float* __restrict__ lin_w,
                                               const float* __restrict__ lin_b,
                                               float* __restrict__ out) {
  int t = threadIdx.x;  // 512 = 64 graphs x 8 classes
  int g = t >> 3, co = t & 7;
  float cnt = (float)counts[g];
  if (cnt < 1.f) cnt = 1.f;
  float inv = 1.f / cnt;
  float v = lin_b[co];
  for (int d = 0; d < DD; ++d) v += (sums[g * DD + d] * inv) * lin_w[d * CCLS + co];
  out[t] = v;
}

extern "C" void kernel_launch(void* const* d_in, const int* in_sizes, int n_in,
                              void* d_out, int out_size, void* d_ws, size_t ws_size,
                              hipStream_t stream) {
  (void)in_sizes; (void)n_in; (void)out_size; (void)ws_size;
  const float* x     = (const float*)d_in[0];
  const float* W     = (const float*)d_in[1];
  const float* b     = (const float*)d_in[2];
  const float* lin_w = (const float*)d_in[3];
  const float* lin_b = (const float*)d_in[4];
  const int*   EI    = (const int*)d_in[5];
  const int*   batch = (const int*)d_in[6];
  float* out = (float*)d_out;

  char* ws = (char*)d_ws;
  uint*   xw    = (uint*)(ws + OFF_XW);       // fp8 table (isd-prescaled)
  uint*   h1    = (uint*)(ws + OFF_H1);       // bf16 packed
  ushort* WbfT  = (ushort*)(ws + OFF_WBT);
  float*  isd   = (float*)(ws + OFF_ISD);
  int*    rp    = (int*)(ws + OFF_RP);
  int*    ci    = (int*)(ws + OFF_CI);
  uint*   bdata = (uint*)(ws + OFF_BD);
  char*   zb    = ws + OFF_ZERO;
  int*    gcur  = (int*)(zb + ZO_GCUR);
  float*  sums  = (float*)(zb + ZO_SUM);
  int*    counts= (int*)(zb + ZO_CNT);

  (void)hipMemsetAsync(zb, 0, ZERO_BYTES, stream);

  k_wprep<<<256, 256, 0, stream>>>(W, WbfT);
  k_part<<<dim3((EE + 4095) / 4096, RR), 256, 0, stream>>>(EI, gcur, bdata);
  k_csr<<<dim3(NBUK, RR), 256, 0, stream>>>(bdata, gcur, isd, rp, ci);

  for (int l = 0; l < LL; ++l) {
    const ushort* WTl_g = WbfT + (size_t)l * RR * DD * DD;
    if (l == 0)
      k_gemm<0><<<(NN + 127) / 128, 256, 0, stream>>>((const void*)x, WTl_g, isd, xw);
    else
      k_gemm<1><<<(NN + 127) / 128, 256, 0, stream>>>((const void*)h1, WTl_g, isd, xw);
    k_agg<<<(NN + 3) / 4, 256, 0, stream>>>(xw, rp, ci, isd,
                                            b + (size_t)l * RR * DD, h1,
                                            (l < LL - 1) ? 1 : 0);
  }
  k_pool<<<(NN + PCHUNK - 1) / PCHUNK, 64, 0, stream>>>(h1, batch, sums, counts);
  k_final<<<1, GG * CCLS, 0, stream>>>(sums, counts, lin_w, lin_b, out);
}